// Round 5
// baseline (312.219 us; speedup 1.0000x reference)
//
#include <hip/hip_runtime.h>
#include <hip/hip_bf16.h>
#include <math.h>

#define Bb 16
#define Tt 64
#define Ff 64
#define MAXE 2048

// ---------------- kprep: block 0 = CSR build; block 1 = weight tables -------
__global__ __launch_bounds__(256) void kprep(
    const int* __restrict__ src, const int* __restrict__ dst, int E,
    const float* __restrict__ W_enc, const float* __restrict__ b_enc,
    const float* __restrict__ W_gat, const float* __restrict__ attn_l,
    const float* __restrict__ attn_r, const float* __restrict__ b_gat,
    int* __restrict__ off, int* __restrict__ csr,
    float* __restrict__ A, float* __restrict__ Bc,
    float* __restrict__ aA, float* __restrict__ aB,
    float* __restrict__ rA, float* __restrict__ rB) {
  __shared__ int s_src[MAXE], s_dst[MAXE];
  __shared__ int cnt[Ff], base[Ff];
  __shared__ __align__(16) float We[64][64], Be[64][64], Wg[64][64];
  __shared__ __align__(16) float As[64][64], Bs[64][64];
  __shared__ float al_s[64], ar_s[64], bg_s[64];
  int t = threadIdx.x;

  if (blockIdx.x == 0) {                       // ---- CSR by dst ----
    for (int e = t; e < E; e += 256) { s_src[e] = src[e]; s_dst[e] = dst[e]; }
    if (t < Ff) cnt[t] = 0;
    __syncthreads();
    for (int e = t; e < E; e += 256) atomicAdd(&cnt[s_dst[e]], 1);
    __syncthreads();
    if (t == 0) {
      int s = 0;
      for (int i = 0; i < Ff; ++i) { base[i] = s; off[i] = s; s += cnt[i]; }
      off[Ff] = s;
    }
    __syncthreads();
    if (t < Ff) {
      int pos = base[t];
      for (int e = 0; e < E; ++e)
        if (s_dst[e] == t) csr[pos++] = s_src[e];
    }
    return;
  }

  // ---- tables: A = We@Wg, Bc = Be@Wg (+b_gat), attn scalar tables ----
  for (int i = t; i < 1024; i += 256) {
    ((float4*)We)[i] = ((const float4*)W_enc)[i];
    ((float4*)Be)[i] = ((const float4*)b_enc)[i];
    ((float4*)Wg)[i] = ((const float4*)W_gat)[i];
  }
  if (t < 64) { al_s[t] = attn_l[t]; ar_s[t] = attn_r[t]; bg_s[t] = b_gat[t]; }
  __syncthreads();
  int n = t >> 2, q = t & 3;
  float accA[16], accB[16];
#pragma unroll
  for (int j = 0; j < 16; ++j) { accA[j] = 0.f; accB[j] = 0.f; }
  for (int k = 0; k < 64; ++k) {
    float we = We[n][k], be = Be[n][k];
#pragma unroll
    for (int c = 0; c < 4; ++c) {
      float4 wg = *(const float4*)&Wg[k][q * 16 + c * 4];
      accA[c*4+0] = fmaf(we, wg.x, accA[c*4+0]); accB[c*4+0] = fmaf(be, wg.x, accB[c*4+0]);
      accA[c*4+1] = fmaf(we, wg.y, accA[c*4+1]); accB[c*4+1] = fmaf(be, wg.y, accB[c*4+1]);
      accA[c*4+2] = fmaf(we, wg.z, accA[c*4+2]); accB[c*4+2] = fmaf(be, wg.z, accB[c*4+2]);
      accA[c*4+3] = fmaf(we, wg.w, accA[c*4+3]); accB[c*4+3] = fmaf(be, wg.w, accB[c*4+3]);
    }
  }
#pragma unroll
  for (int c = 0; c < 4; ++c) {
    float4 va, vb, vbg;
    va.x = accA[c*4+0]; va.y = accA[c*4+1]; va.z = accA[c*4+2]; va.w = accA[c*4+3];
    vb.x = accB[c*4+0]; vb.y = accB[c*4+1]; vb.z = accB[c*4+2]; vb.w = accB[c*4+3];
    vbg.x = vb.x + bg_s[q*16+c*4+0]; vbg.y = vb.y + bg_s[q*16+c*4+1];
    vbg.z = vb.z + bg_s[q*16+c*4+2]; vbg.w = vb.w + bg_s[q*16+c*4+3];
    *(float4*)&As[n][q*16 + c*4] = va;
    *(float4*)&Bs[n][q*16 + c*4] = vb;       // unfolded (attn tables)
    *(float4*)&A[n*64 + q*16 + c*4] = va;
    *(float4*)&Bc[n*64 + q*16 + c*4] = vbg;  // folded (+b_gat; Σα=1 makes it exact)
  }
  __syncthreads();
  float sa = 0.f, sb = 0.f, sra = 0.f, srb = 0.f;
#pragma unroll
  for (int j = 0; j < 16; ++j) {
    float alv = al_s[q*16 + j], arv = ar_s[q*16 + j];
    float av = As[n][q*16 + j], bv = Bs[n][q*16 + j];
    sa  = fmaf(av, alv, sa);  sb  = fmaf(bv, alv, sb);
    sra = fmaf(av, arv, sra); srb = fmaf(bv, arv, srb);
  }
  aA[t] = sa; aB[t] = sb; rA[t] = sra; rB[t] = srb;
}

// ---------------- fused: GAT(f) + grouped xW + GRU + decode, per (f,b) ------
__device__ __forceinline__ float qsum(float v) {
  v += __int_as_float(__builtin_amdgcn_mov_dpp(__float_as_int(v), 0xB1, 0xF, 0xF, true));
  v += __int_as_float(__builtin_amdgcn_mov_dpp(__float_as_int(v), 0x4E, 0xF, 0xF, true));
  return v;
}
// broadcast quad lane c0 to all 4 quad lanes; c0 must fold to a constant
// (switch arms carry the literal dpp_ctrl the builtin requires)
__device__ __forceinline__ float qbc(float v, int c0) {
  switch (c0) {
    case 0:  return __int_as_float(__builtin_amdgcn_mov_dpp(__float_as_int(v), 0x00, 0xF, 0xF, true));
    case 1:  return __int_as_float(__builtin_amdgcn_mov_dpp(__float_as_int(v), 0x55, 0xF, 0xF, true));
    case 2:  return __int_as_float(__builtin_amdgcn_mov_dpp(__float_as_int(v), 0xAA, 0xF, 0xF, true));
    default: return __int_as_float(__builtin_amdgcn_mov_dpp(__float_as_int(v), 0xFF, 0xF, 0xF, true));
  }
}

__global__ __launch_bounds__(256, 4) void k_fused(
    const float* __restrict__ hist, const float* __restrict__ Ag,
    const float* __restrict__ Bg, const float* __restrict__ aAg,
    const float* __restrict__ aBg, const float* __restrict__ rAg,
    const float* __restrict__ rBg, const int* __restrict__ off,
    const int* __restrict__ csr,
    const float* __restrict__ W_ih, const float* __restrict__ W_hh,
    const float* __restrict__ b_ih, const float* __restrict__ b_hh,
    const float* __restrict__ W_dec, const float* __restrict__ b_dec,
    float* __restrict__ hid, float* __restrict__ ans) {
  __shared__ __align__(16) float xsl[4096];       // x, XOR-swizzled (column reads)
  __shared__ __align__(16) float gsl[64 * 68];    // g, padded rows (row+col reads)
  __shared__ __align__(16) float h_s[2][64];
  __shared__ __align__(16) float hbuf[2][8][64];
  __shared__ __align__(16) float aA_s[256], aB_s[256];
  __shared__ int csr_s[96];
  int blk = blockIdx.x;
  int f = blk & 63, b = blk >> 6;
  int t = threadIdx.x;

  // ---- stage x (swizzled), tables, csr ----
  const float* histb = hist + (size_t)b * 4096;
#pragma unroll
  for (int r = 0; r < 4; ++r) {
    int g4 = r * 256 + t;
    float4 v = ((const float4*)histb)[g4];
    int row0 = g4 >> 4, ch = g4 & 15;
    ((float4*)xsl)[(row0 << 4) + (ch ^ (row0 & 7))] = v;
  }
  if (t < 64) {
    ((float4*)aA_s)[t] = ((const float4*)aAg)[t];
    ((float4*)aB_s)[t] = ((const float4*)aBg)[t];
    h_s[0][t] = 0.f; h_s[1][t] = 0.f;
  }
  int o0 = off[f], deg = off[f + 1] - o0;
  if (t < 96 && t < deg) csr_s[t] = csr[o0 + t];
  int tts = t >> 2, hh = t & 3;
  float rAf = rAg[(f << 2) + hh], rBf = rBg[(f << 2) + hh];
  __syncthreads();

  // ---- GAT for dst=f, single pass (no max subtraction; |e| bounded) ----
  int s7 = tts & 7;
  float xf = xsl[(tts << 6) + ((((f >> 2) ^ s7) << 2) | (f & 3))];
  float er = fmaf(xf, rAf, rBf);
  float acc[16];
#pragma unroll
  for (int j = 0; j < 16; ++j) acc[j] = 0.f;
  float den = 0.f;
  for (int i = 0; i < deg; ++i) {
    int s = (i < 96) ? csr_s[i] : csr[o0 + i];
    float xs = xsl[(tts << 6) + ((((s >> 2) ^ s7) << 2) | (s & 3))];
    float e = fmaf(xs, aA_s[(s << 2) + hh], aB_s[(s << 2) + hh]) + er;
    e = fmaxf(e, 0.2f * e);
    float p = __expf(e);
    den += p;
    const float4* Ar = (const float4*)(Ag + (s << 6) + (hh << 4));
    const float4* Br = (const float4*)(Bg + (s << 6) + (hh << 4));
#pragma unroll
    for (int c = 0; c < 4; ++c) {
      float4 a4 = Ar[c], b4 = Br[c];
      acc[c*4+0] = fmaf(p, fmaf(xs, a4.x, b4.x), acc[c*4+0]);
      acc[c*4+1] = fmaf(p, fmaf(xs, a4.y, b4.y), acc[c*4+1]);
      acc[c*4+2] = fmaf(p, fmaf(xs, a4.z, b4.z), acc[c*4+2]);
      acc[c*4+3] = fmaf(p, fmaf(xs, a4.w, b4.w), acc[c*4+3]);
    }
  }
  float invd = __builtin_amdgcn_rcpf(den);
#pragma unroll
  for (int c = 0; c < 4; ++c) {
    float4 o;
    o.x = acc[c*4+0] * invd; o.y = acc[c*4+1] * invd;
    o.z = acc[c*4+2] * invd; o.w = acc[c*4+3] * invd;
    *(float4*)&gsl[tts * 68 + (hh << 4) + (c << 2)] = o;
  }

  // ---- persistent GRU state: Whh slices in regs, biases, decode weights ----
  int row = t >> 2, kg = t & 3;
  const float* Wh = W_hh + f * 12288 + (kg << 4);
  float wh0[16], wh1[16], wh2[16];
#pragma unroll
  for (int c = 0; c < 4; ++c) {
    *(float4*)&wh0[c*4] = *(const float4*)(Wh + (row << 6) + (c << 2));
    *(float4*)&wh1[c*4] = *(const float4*)(Wh + ((64 + row) << 6) + (c << 2));
    *(float4*)&wh2[c*4] = *(const float4*)(Wh + ((128 + row) << 6) + (c << 2));
  }
  float bR  = b_ih[f*192 + row]       + b_hh[f*192 + row];
  float bZ  = b_ih[f*192 + 64 + row]  + b_hh[f*192 + 64 + row];
  float bXN = b_ih[f*192 + 128 + row];
  float bHN = b_hh[f*192 + 128 + row];
  int j2 = t & 31;
  float wd0 = W_dec[(f << 6) + j2], wd1 = W_dec[(f << 6) + 32 + j2];
  float bdec = b_dec[f];
  size_t hidbase = (size_t)b * 262144 + (f << 6);
  unsigned long long wpB = (unsigned long long)(W_ih + f * 12288);
  float hreg = 0.f;
  __syncthreads();   // g visible to all

#pragma unroll 1
  for (int G = 0; G < 4; ++G) {
    // ---- phase A: xW[ts][gate][row] for this 16-step group, into 12 regs ----
    asm volatile("" : "+s"(wpB));   // defeat LICM: keep wig loads inside loop
    const float* WiB = (const float*)wpB + (kg << 4);
    const float* gbase = &gsl[(G << 4) * 68];
    float xw[4][3];
#pragma unroll
    for (int g = 0; g < 3; ++g) {
      float wig[16];
#pragma unroll
      for (int c = 0; c < 4; ++c)
        *(float4*)&wig[c*4] = *(const float4*)(WiB + ((g*64 + row) << 6) + (c << 2));
#pragma unroll
      for (int ts = 0; ts < 16; ++ts) {
        float p = 0.f;
#pragma unroll
        for (int c = 0; c < 4; ++c) {
          float4 gv = *(const float4*)&gbase[ts * 68 + (kg << 4) + (c << 2)];
          p = fmaf(gv.x, wig[c*4+0], p);
          p = fmaf(gv.y, wig[c*4+1], p);
          p = fmaf(gv.z, wig[c*4+2], p);
          p = fmaf(gv.w, wig[c*4+3], p);
        }
        p = qsum(p);                        // full 64-k sum, all quad lanes
        const int c0 = ts >> 2, u = ts & 3;
        if (c0 == 0) xw[u][g] = p;
        else         xw[u][g] = (kg == c0) ? p : xw[u][g];
      }
    }

    // ---- 16 serial GRU steps ----
#pragma unroll
    for (int st = 0; st < 16; ++st) {
      const int cur = st & 1, c0 = st >> 2, u = st & 3;
      float xr = qbc(xw[u][0], c0);
      float xz = qbc(xw[u][1], c0);
      float xn = qbc(xw[u][2], c0);
      float pr = 0.f, pz = 0.f, pn = 0.f;
#pragma unroll
      for (int c = 0; c < 4; ++c) {
        float4 hv = *(const float4*)&h_s[cur][(kg << 4) + (c << 2)];
        pr = fmaf(hv.x, wh0[c*4+0], pr); pr = fmaf(hv.y, wh0[c*4+1], pr);
        pr = fmaf(hv.z, wh0[c*4+2], pr); pr = fmaf(hv.w, wh0[c*4+3], pr);
        pz = fmaf(hv.x, wh1[c*4+0], pz); pz = fmaf(hv.y, wh1[c*4+1], pz);
        pz = fmaf(hv.z, wh1[c*4+2], pz); pz = fmaf(hv.w, wh1[c*4+3], pz);
        pn = fmaf(hv.x, wh2[c*4+0], pn); pn = fmaf(hv.y, wh2[c*4+1], pn);
        pn = fmaf(hv.z, wh2[c*4+2], pn); pn = fmaf(hv.w, wh2[c*4+3], pn);
      }
      pr = qsum(pr); pz = qsum(pz); pn = qsum(pn);
      float rr = __builtin_amdgcn_rcpf(1.f + __expf(-(pr + xr + bR)));
      float zz = __builtin_amdgcn_rcpf(1.f + __expf(-(pz + xz + bZ)));
      float pre = fmaf(rr, pn + bHN, xn + bXN);
      float nn = 1.f - 2.f * __builtin_amdgcn_rcpf(1.f + __expf(2.f * pre));
      float hnew = fmaf(zz, hreg - nn, nn);
      hreg = hnew;
      if (kg == 0) h_s[cur ^ 1][row] = hnew;
      if (kg == 1) hbuf[(st >> 3) & 1][st & 7][row] = hnew;
      __syncthreads();
      if ((st & 7) == 7) {                  // flush 8 h-rows + fused decode
        const int gsel = (st >> 3) & 1;
        int ts0 = (G << 4) + st - 7;
        if (t < 128) {
          int i = t >> 4, j = t & 15;
          float4 hv4 = *(const float4*)&hbuf[gsel][i][j << 2];
          *(float4*)&hid[hidbase + (size_t)(ts0 + i) * 4096 + (j << 2)] = hv4;
        }
        int i2 = t >> 5;
        float part = hbuf[gsel][i2][j2] * wd0 + hbuf[gsel][i2][j2 + 32] * wd1;
        part += __shfl_xor(part, 1);  part += __shfl_xor(part, 2);
        part += __shfl_xor(part, 4);  part += __shfl_xor(part, 8);
        part += __shfl_xor(part, 16);
        if (j2 == 0) ans[((b << 6) + ts0 + i2) * 64 + f] = part + bdec;
      }
    }
  }
}

extern "C" void kernel_launch(void* const* d_in, const int* in_sizes, int n_in,
                              void* d_out, int out_size, void* d_ws, size_t ws_size,
                              hipStream_t stream) {
  const float* hist   = (const float*)d_in[0];
  const int* src      = (const int*)d_in[1];
  const int* dst      = (const int*)d_in[2];
  const float* W_enc  = (const float*)d_in[3];
  const float* b_enc  = (const float*)d_in[4];
  const float* W_gat  = (const float*)d_in[5];
  const float* attn_l = (const float*)d_in[6];
  const float* attn_r = (const float*)d_in[7];
  const float* b_gat  = (const float*)d_in[8];
  const float* W_ih   = (const float*)d_in[9];
  const float* W_hh   = (const float*)d_in[10];
  const float* b_ih   = (const float*)d_in[11];
  const float* b_hh   = (const float*)d_in[12];
  const float* W_dec  = (const float*)d_in[13];
  const float* b_dec  = (const float*)d_in[14];
  int E = in_sizes[1];

  float* ans = (float*)d_out;
  float* hid = (float*)d_out + Bb * Tt * Ff;   // [B,T,F,H]

  int* off   = (int*)d_ws;                     // 65 used (reserve 256)
  int* csr   = off + 256;                      // E used (reserve 2048)
  float* A   = (float*)(csr + 2048);           // 4096
  float* Bc  = A + 4096;                       // 4096 (b_gat folded)
  float* aA  = Bc + 4096;                      // 256
  float* aB  = aA + 256;
  float* rA  = aB + 256;
  float* rB  = rA + 256;

  hipLaunchKernelGGL(kprep, dim3(2), dim3(256), 0, stream,
                     src, dst, E, W_enc, b_enc, W_gat, attn_l, attn_r, b_gat,
                     off, csr, A, Bc, aA, aB, rA, rB);
  hipLaunchKernelGGL(k_fused, dim3(Ff * Bb), dim3(256), 0, stream,
                     hist, A, Bc, aA, aB, rA, rB, off, csr,
                     W_ih, W_hh, b_ih, b_hh, W_dec, b_dec, hid, ans);
}

// Round 6
// 200.901 us; speedup vs baseline: 1.5541x; 1.5541x over previous
//
#include <hip/hip_runtime.h>
#include <hip/hip_bf16.h>
#include <math.h>

#define Bb 16
#define Tt 64
#define Ff 64
#define MAXE 2048

// ---------------- kprep: block 0 = CSR build; block 1 = weight tables -------
__global__ __launch_bounds__(256) void kprep(
    const int* __restrict__ src, const int* __restrict__ dst, int E,
    const float* __restrict__ W_enc, const float* __restrict__ b_enc,
    const float* __restrict__ W_gat, const float* __restrict__ attn_l,
    const float* __restrict__ attn_r, const float* __restrict__ b_gat,
    int* __restrict__ off, int* __restrict__ csr,
    float* __restrict__ A, float* __restrict__ Bc,
    float* __restrict__ aA, float* __restrict__ aB,
    float* __restrict__ rA, float* __restrict__ rB) {
  __shared__ int s_src[MAXE], s_dst[MAXE];
  __shared__ int cnt[Ff], base[Ff];
  __shared__ __align__(16) float We[64][64], Be[64][64], Wg[64][64];
  __shared__ __align__(16) float As[64][64], Bs[64][64];
  __shared__ float al_s[64], ar_s[64], bg_s[64];
  int t = threadIdx.x;

  if (blockIdx.x == 0) {                       // ---- CSR by dst ----
    for (int e = t; e < E; e += 256) { s_src[e] = src[e]; s_dst[e] = dst[e]; }
    if (t < Ff) cnt[t] = 0;
    __syncthreads();
    for (int e = t; e < E; e += 256) atomicAdd(&cnt[s_dst[e]], 1);
    __syncthreads();
    if (t == 0) {
      int s = 0;
      for (int i = 0; i < Ff; ++i) { base[i] = s; off[i] = s; s += cnt[i]; }
      off[Ff] = s;
    }
    __syncthreads();
    if (t < Ff) {
      int pos = base[t];
      for (int e = 0; e < E; ++e)
        if (s_dst[e] == t) csr[pos++] = s_src[e];
    }
    return;
  }

  // ---- tables: A = We@Wg, Bc = Be@Wg (+b_gat), attn scalar tables ----
  for (int i = t; i < 1024; i += 256) {
    ((float4*)We)[i] = ((const float4*)W_enc)[i];
    ((float4*)Be)[i] = ((const float4*)b_enc)[i];
    ((float4*)Wg)[i] = ((const float4*)W_gat)[i];
  }
  if (t < 64) { al_s[t] = attn_l[t]; ar_s[t] = attn_r[t]; bg_s[t] = b_gat[t]; }
  __syncthreads();
  int n = t >> 2, q = t & 3;
  float accA[16], accB[16];
#pragma unroll
  for (int j = 0; j < 16; ++j) { accA[j] = 0.f; accB[j] = 0.f; }
  for (int k = 0; k < 64; ++k) {
    float we = We[n][k], be = Be[n][k];
#pragma unroll
    for (int c = 0; c < 4; ++c) {
      float4 wg = *(const float4*)&Wg[k][q * 16 + c * 4];
      accA[c*4+0] = fmaf(we, wg.x, accA[c*4+0]); accB[c*4+0] = fmaf(be, wg.x, accB[c*4+0]);
      accA[c*4+1] = fmaf(we, wg.y, accA[c*4+1]); accB[c*4+1] = fmaf(be, wg.y, accB[c*4+1]);
      accA[c*4+2] = fmaf(we, wg.z, accA[c*4+2]); accB[c*4+2] = fmaf(be, wg.z, accB[c*4+2]);
      accA[c*4+3] = fmaf(we, wg.w, accA[c*4+3]); accB[c*4+3] = fmaf(be, wg.w, accB[c*4+3]);
    }
  }
#pragma unroll
  for (int c = 0; c < 4; ++c) {
    float4 va, vb, vbg;
    va.x = accA[c*4+0]; va.y = accA[c*4+1]; va.z = accA[c*4+2]; va.w = accA[c*4+3];
    vb.x = accB[c*4+0]; vb.y = accB[c*4+1]; vb.z = accB[c*4+2]; vb.w = accB[c*4+3];
    vbg.x = vb.x + bg_s[q*16+c*4+0]; vbg.y = vb.y + bg_s[q*16+c*4+1];
    vbg.z = vb.z + bg_s[q*16+c*4+2]; vbg.w = vb.w + bg_s[q*16+c*4+3];
    *(float4*)&As[n][q*16 + c*4] = va;
    *(float4*)&Bs[n][q*16 + c*4] = vb;       // unfolded (attn tables)
    *(float4*)&A[n*64 + q*16 + c*4] = va;
    *(float4*)&Bc[n*64 + q*16 + c*4] = vbg;  // folded (+b_gat; Σα=1 makes it exact)
  }
  __syncthreads();
  float sa = 0.f, sb = 0.f, sra = 0.f, srb = 0.f;
#pragma unroll
  for (int j = 0; j < 16; ++j) {
    float alv = al_s[q*16 + j], arv = ar_s[q*16 + j];
    float av = As[n][q*16 + j], bv = Bs[n][q*16 + j];
    sa  = fmaf(av, alv, sa);  sb  = fmaf(bv, alv, sb);
    sra = fmaf(av, arv, sra); srb = fmaf(bv, arv, srb);
  }
  aA[t] = sa; aB[t] = sb; rA[t] = sra; rB[t] = srb;
}

// ---------------- fused: GAT(f) + grouped xW (LDS) + GRU + decode -----------
__device__ __forceinline__ float qsum(float v) {
  v += __int_as_float(__builtin_amdgcn_mov_dpp(__float_as_int(v), 0xB1, 0xF, 0xF, true));
  v += __int_as_float(__builtin_amdgcn_mov_dpp(__float_as_int(v), 0x4E, 0xF, 0xF, true));
  return v;
}

__global__ __launch_bounds__(256, 4) void k_fused(
    const float* __restrict__ hist, const float* __restrict__ Ag,
    const float* __restrict__ Bg, const float* __restrict__ aAg,
    const float* __restrict__ aBg, const float* __restrict__ rAg,
    const float* __restrict__ rBg, const int* __restrict__ off,
    const int* __restrict__ csr,
    const float* __restrict__ W_ih, const float* __restrict__ W_hh,
    const float* __restrict__ b_ih, const float* __restrict__ b_hh,
    const float* __restrict__ W_dec, const float* __restrict__ b_dec,
    float* __restrict__ hid, float* __restrict__ ans) {
  __shared__ __align__(16) float xsl[4096];     // x (swizzled); reused: xw[16][64][4]
  __shared__ __align__(16) float gsl[64 * 68];  // g, padded rows
  __shared__ __align__(16) float h_s[2][64];
  __shared__ __align__(16) float uni[1024];     // aA/aB (GAT) -> hbuf[2][8][64] (GRU)
  __shared__ int csr_s[96];
  float* aA_s = uni;
  float* aB_s = uni + 256;
  float (*hbuf)[8][64] = (float (*)[8][64])uni;
  int blk = blockIdx.x;
  int f = blk & 63, b = blk >> 6;
  int t = threadIdx.x;

  // ---- stage x (swizzled), tables, csr ----
  const float* histb = hist + (size_t)b * 4096;
#pragma unroll
  for (int r = 0; r < 4; ++r) {
    int g4 = r * 256 + t;
    float4 v = ((const float4*)histb)[g4];
    int row0 = g4 >> 4, ch = g4 & 15;
    ((float4*)xsl)[(row0 << 4) + (ch ^ (row0 & 7))] = v;
  }
  if (t < 64) {
    ((float4*)aA_s)[t] = ((const float4*)aAg)[t];
    ((float4*)aB_s)[t] = ((const float4*)aBg)[t];
    h_s[0][t] = 0.f; h_s[1][t] = 0.f;
  }
  int o0 = off[f], deg = off[f + 1] - o0;
  if (t < 96 && t < deg) csr_s[t] = csr[o0 + t];
  int tts = t >> 2, hh = t & 3;
  float rAf = rAg[(f << 2) + hh], rBf = rBg[(f << 2) + hh];
  __syncthreads();

  // ---- GAT for dst=f, single pass (no max subtraction; |e| bounded) ----
  int s7 = tts & 7;
  float xf = xsl[(tts << 6) + ((((f >> 2) ^ s7) << 2) | (f & 3))];
  float er = fmaf(xf, rAf, rBf);
  float acc[16];
#pragma unroll
  for (int j = 0; j < 16; ++j) acc[j] = 0.f;
  float den = 0.f;
  for (int i = 0; i < deg; ++i) {
    int s = (i < 96) ? csr_s[i] : csr[o0 + i];
    float xs = xsl[(tts << 6) + ((((s >> 2) ^ s7) << 2) | (s & 3))];
    float e = fmaf(xs, aA_s[(s << 2) + hh], aB_s[(s << 2) + hh]) + er;
    e = fmaxf(e, 0.2f * e);
    float p = __expf(e);
    den += p;
    const float4* Ar = (const float4*)(Ag + (s << 6) + (hh << 4));
    const float4* Br = (const float4*)(Bg + (s << 6) + (hh << 4));
#pragma unroll
    for (int c = 0; c < 4; ++c) {
      float4 a4 = Ar[c], b4 = Br[c];
      acc[c*4+0] = fmaf(p, fmaf(xs, a4.x, b4.x), acc[c*4+0]);
      acc[c*4+1] = fmaf(p, fmaf(xs, a4.y, b4.y), acc[c*4+1]);
      acc[c*4+2] = fmaf(p, fmaf(xs, a4.z, b4.z), acc[c*4+2]);
      acc[c*4+3] = fmaf(p, fmaf(xs, a4.w, b4.w), acc[c*4+3]);
    }
  }
  float invd = __builtin_amdgcn_rcpf(den);
#pragma unroll
  for (int c = 0; c < 4; ++c) {
    float4 o;
    o.x = acc[c*4+0] * invd; o.y = acc[c*4+1] * invd;
    o.z = acc[c*4+2] * invd; o.w = acc[c*4+3] * invd;
    *(float4*)&gsl[tts * 68 + (hh << 4) + (c << 2)] = o;
  }

  // ---- persistent GRU state: Whh slices in regs, biases, decode weights ----
  int row = t >> 2, kg = t & 3;
  const float* Wh = W_hh + f * 12288 + (kg << 4);
  float wh0[16], wh1[16], wh2[16];
#pragma unroll
  for (int c = 0; c < 4; ++c) {
    *(float4*)&wh0[c*4] = *(const float4*)(Wh + (row << 6) + (c << 2));
    *(float4*)&wh1[c*4] = *(const float4*)(Wh + ((64 + row) << 6) + (c << 2));
    *(float4*)&wh2[c*4] = *(const float4*)(Wh + ((128 + row) << 6) + (c << 2));
  }
  float bR  = b_ih[f*192 + row]       + b_hh[f*192 + row];
  float bZ  = b_ih[f*192 + 64 + row]  + b_hh[f*192 + 64 + row];
  float bXN = b_ih[f*192 + 128 + row];
  float bHN = b_hh[f*192 + 128 + row];
  int j2 = t & 31;
  float wd0 = W_dec[(f << 6) + j2], wd1 = W_dec[(f << 6) + 32 + j2];
  float bdec = b_dec[f];
  size_t hidbase = (size_t)b * 262144 + (f << 6);
  unsigned long long wpB = (unsigned long long)(W_ih + f * 12288);
  float hreg = 0.f;
  float* xw = xsl;               // [ts][row][4]; rows are wave-private
  __syncthreads();               // g visible; xsl reads done; aA/aB reads done

#pragma unroll 1
  for (int G = 0; G < 4; ++G) {
    // ---- phase A: xw[ts][row][{r,z,n}] for this 16-step group (LDS) ----
    asm volatile("" : "+s"(wpB));   // defeat LICM: reload wig per group
    const float* WiB = (const float*)wpB + (kg << 4);
    const float* gbase = &gsl[(G << 4) * 68];
#pragma unroll 1
    for (int g = 0; g < 3; ++g) {
      float wig[16];
#pragma unroll
      for (int c = 0; c < 4; ++c)
        *(float4*)&wig[c*4] = *(const float4*)(WiB + ((g*64 + row) << 6) + (c << 2));
#pragma unroll 4
      for (int ts = 0; ts < 16; ++ts) {
        float p = 0.f;
#pragma unroll
        for (int c = 0; c < 4; ++c) {
          float4 gv = *(const float4*)&gbase[ts * 68 + (kg << 4) + (c << 2)];
          p = fmaf(gv.x, wig[c*4+0], p);
          p = fmaf(gv.y, wig[c*4+1], p);
          p = fmaf(gv.z, wig[c*4+2], p);
          p = fmaf(gv.w, wig[c*4+3], p);
        }
        p = qsum(p);                       // full 64-k sum on all quad lanes
        if (kg == 0) xw[(((ts << 6) + row) << 2) + g] = p;
      }
    }

    // ---- 16 serial GRU steps ----
#pragma unroll 2
    for (int st = 0; st < 16; ++st) {
      const int cur = st & 1;
      float4 xg = *(const float4*)&xw[((st << 6) + row) << 2];  // {xr,xz,xn,-}
      float pr = 0.f, pz = 0.f, pn = 0.f;
#pragma unroll
      for (int c = 0; c < 4; ++c) {
        float4 hv = *(const float4*)&h_s[cur][(kg << 4) + (c << 2)];
        pr = fmaf(hv.x, wh0[c*4+0], pr); pr = fmaf(hv.y, wh0[c*4+1], pr);
        pr = fmaf(hv.z, wh0[c*4+2], pr); pr = fmaf(hv.w, wh0[c*4+3], pr);
        pz = fmaf(hv.x, wh1[c*4+0], pz); pz = fmaf(hv.y, wh1[c*4+1], pz);
        pz = fmaf(hv.z, wh1[c*4+2], pz); pz = fmaf(hv.w, wh1[c*4+3], pz);
        pn = fmaf(hv.x, wh2[c*4+0], pn); pn = fmaf(hv.y, wh2[c*4+1], pn);
        pn = fmaf(hv.z, wh2[c*4+2], pn); pn = fmaf(hv.w, wh2[c*4+3], pn);
      }
      pr = qsum(pr); pz = qsum(pz); pn = qsum(pn);
      float rr = __builtin_amdgcn_rcpf(1.f + __expf(-(pr + xg.x + bR)));
      float zz = __builtin_amdgcn_rcpf(1.f + __expf(-(pz + xg.y + bZ)));
      float pre = fmaf(rr, pn + bHN, xg.z + bXN);
      float nn = 1.f - 2.f * __builtin_amdgcn_rcpf(1.f + __expf(2.f * pre));
      float hnew = fmaf(zz, hreg - nn, nn);
      hreg = hnew;
      if (kg == 0) h_s[cur ^ 1][row] = hnew;
      if (kg == 1) hbuf[(st >> 3) & 1][st & 7][row] = hnew;
      __syncthreads();
      if ((st & 7) == 7) {                  // flush 8 h-rows + fused decode
        const int gsel = (st >> 3) & 1;
        int ts0 = (G << 4) + st - 7;
        if (t < 128) {
          int i = t >> 4, j = t & 15;
          float4 hv4 = *(const float4*)&hbuf[gsel][i][j << 2];
          *(float4*)&hid[hidbase + (size_t)(ts0 + i) * 4096 + (j << 2)] = hv4;
        }
        int i2 = t >> 5;
        float part = hbuf[gsel][i2][j2] * wd0 + hbuf[gsel][i2][j2 + 32] * wd1;
        part += __shfl_xor(part, 1);  part += __shfl_xor(part, 2);
        part += __shfl_xor(part, 4);  part += __shfl_xor(part, 8);
        part += __shfl_xor(part, 16);
        if (j2 == 0) ans[((b << 6) + ts0 + i2) * 64 + f] = part + bdec;
      }
    }
  }
}

extern "C" void kernel_launch(void* const* d_in, const int* in_sizes, int n_in,
                              void* d_out, int out_size, void* d_ws, size_t ws_size,
                              hipStream_t stream) {
  const float* hist   = (const float*)d_in[0];
  const int* src      = (const int*)d_in[1];
  const int* dst      = (const int*)d_in[2];
  const float* W_enc  = (const float*)d_in[3];
  const float* b_enc  = (const float*)d_in[4];
  const float* W_gat  = (const float*)d_in[5];
  const float* attn_l = (const float*)d_in[6];
  const float* attn_r = (const float*)d_in[7];
  const float* b_gat  = (const float*)d_in[8];
  const float* W_ih   = (const float*)d_in[9];
  const float* W_hh   = (const float*)d_in[10];
  const float* b_ih   = (const float*)d_in[11];
  const float* b_hh   = (const float*)d_in[12];
  const float* W_dec  = (const float*)d_in[13];
  const float* b_dec  = (const float*)d_in[14];
  int E = in_sizes[1];

  float* ans = (float*)d_out;
  float* hid = (float*)d_out + Bb * Tt * Ff;   // [B,T,F,H]

  int* off   = (int*)d_ws;                     // 65 used (reserve 256)
  int* csr   = off + 256;                      // E used (reserve 2048)
  float* A   = (float*)(csr + 2048);           // 4096
  float* Bc  = A + 4096;                       // 4096 (b_gat folded)
  float* aA  = Bc + 4096;                      // 256
  float* aB  = aA + 256;
  float* rA  = aB + 256;
  float* rB  = rA + 256;

  hipLaunchKernelGGL(kprep, dim3(2), dim3(256), 0, stream,
                     src, dst, E, W_enc, b_enc, W_gat, attn_l, attn_r, b_gat,
                     off, csr, A, Bc, aA, aB, rA, rB);
  hipLaunchKernelGGL(k_fused, dim3(Ff * Bb), dim3(256), 0, stream,
                     hist, A, Bc, aA, aB, rA, rB, off, csr,
                     W_ih, W_hh, b_ih, b_hh, W_dec, b_dec, hid, ans);
}